// Round 3
// baseline (3259.926 us; speedup 1.0000x reference)
//
#include <hip/hip_runtime.h>
#include <math.h>

#define B_ 8192
#define T_ 30
#define H_ 256
#define NG_ 1024
#define DT_ 0.03f
#define RB 32            // batch rows per persistent block
#define NBLK (B_ / RB)   // 256

typedef __attribute__((ext_vector_type(8))) short short8;
typedef __attribute__((ext_vector_type(4))) float f32x4;

__device__ inline float bf2f(unsigned short u) {
    unsigned int x = ((unsigned int)u) << 16;
    return __builtin_bit_cast(float, x);
}
__device__ inline unsigned short f2bf(float f) {
    unsigned int x = __builtin_bit_cast(unsigned int, f);
    return (unsigned short)((x + 0x7FFF + ((x >> 16) & 1)) >> 16);
}
__device__ inline float fast_tanh(float x) {
    float e = __expf(2.f * x);
    return 1.f - 2.f / (e + 1.f);
}
__device__ inline float fast_sigmoid(float x) {
    return 1.f / (1.f + __expf(-x));
}

// ---------- fused fold+permute: WxP[r][n'] = (W1 @ W2)[r][co(n')], bfP[n'] = (b1@W2+bih+bhh)[co] ----------
// n' = bN*64 + g*16 + j  <->  co = g*256 + bN*16 + j
__global__ void fold_perm_kernel(const float* __restrict__ W1, const float* __restrict__ b1,
                                 const float* __restrict__ W2,
                                 const float* __restrict__ bih, const float* __restrict__ bhh,
                                 float* __restrict__ WxP, float* __restrict__ bfP) {
    __shared__ float sP[4][64];
    const int t63 = threadIdx.x & 63;
    const int kc = threadIdx.x >> 6;
    int o = blockIdx.x * 64 + t63;          // 0..5119  (r=4 is the bias row)
    int r = o >> 10;
    int np = o & 1023;
    int bN = np >> 6, g = (np >> 4) & 3, j = np & 15;
    int co = g * 256 + bN * 16 + j;
    const float* w1row = (r < 4) ? (W1 + r * 128) : b1;
    float acc = 0.f;
    #pragma unroll 8
    for (int k = kc * 32; k < kc * 32 + 32; ++k)
        acc = fmaf(w1row[k], W2[k * NG_ + co], acc);
    sP[kc][t63] = acc;
    __syncthreads();
    if (kc == 0) {
        acc = sP[0][t63] + sP[1][t63] + sP[2][t63] + sP[3][t63];
        if (r < 4) WxP[r * NG_ + np] = acc;
        else       bfP[np] = acc + bih[co] + bhh[co];
    }
}

// WhP[n'][k] = bf16(Whh[k][co(n')])   (1024 x 256)  -- verified R2
__global__ void prep_whp_kernel(const float* __restrict__ W, unsigned short* __restrict__ WhP) {
    int id = blockIdx.x * blockDim.x + threadIdx.x;
    int np = id >> 8, k = id & 255;
    int bN = np >> 6, g = (np >> 4) & 3, j = np & 15;
    int co = g * 256 + bN * 16 + j;
    WhP[id] = f2bf(W[(size_t)k * NG_ + co]);
}

// WT[m][n][k] = bf16(W_m[k][n]) batched over 9 matrices (mu0..3, lv0..3, dec_init)
__global__ void prep_wt_all_kernel(const float* __restrict__ muW, const float* __restrict__ lvW,
                                   const float* __restrict__ diW, unsigned short* __restrict__ WT9) {
    int m = blockIdx.y;
    const float* src = (m < 4) ? muW + (size_t)m * 65536
                     : (m < 8) ? lvW + (size_t)(m - 4) * 65536
                               : diW;
    int id = blockIdx.x * 256 + threadIdx.x;
    int n = id >> 8, k = id & 255;
    WT9[(size_t)m * 65536 + id] = f2bf(src[k * H_ + n]);
}

// ---------- rel input + expert passthrough ----------
__global__ void rel_kernel(const float* __restrict__ traj, float* __restrict__ rel,
                           float4* __restrict__ expert) {
    int id = blockIdx.x * blockDim.x + threadIdx.x;
    if (id >= B_ * T_) return;
    int t = id % T_;
    const float* p = traj + (size_t)id * 4;
    float x = p[0], y = p[1];
    if (t > 0) { x -= p[-4]; y -= p[-3]; }
    float* o = rel + (size_t)id * 4;
    o[0] = x; o[1] = y; o[2] = p[2]; o[3] = p[3];
    expert[id] = ((const float4*)traj)[id];
}

// ---------- persistent LSTM: one block = 32 batch rows, all T steps in-kernel ----------
// LDS byte layout:
//  sB   [128][256] bf16 swizzled      0      .. 65536
//  cL   [32][260]  f32               65536  .. 98816
//  hL   [32][264]  bf16              98816  .. 115712
//  wxL  [4][1024]  f32              115712  .. 132096
//  bfL  [1024]     f32              132096  .. 136192
//  WcL  [256][2]   f32              136192  .. 138240
//  sL   [32][4]    f32              138240  .. 138752
//  redL [32][8][2] f32              138752  .. 140800
#define SMEM_BYTES 140800

template <int DEC>
__global__ __launch_bounds__(256, 1) void lstm_persist_kernel(
    const float* __restrict__ rel,            // enc only: [B][T][4]
    const unsigned short* __restrict__ WhP,   // [1024][256] bf16 permuted
    const float* __restrict__ WxP,            // [4][1024] permuted
    const float* __restrict__ bfP,            // [1024] permuted
    const float* __restrict__ cInit,          // dec only: [B][256] f32
    const unsigned short* __restrict__ hInit, // dec only: [B][256] bf16
    const float* __restrict__ initS,          // dec only: [B][4]
    const float* __restrict__ Wc,             // dec only: [256][2]
    const float* __restrict__ bc,             // dec only: [2]
    unsigned short* __restrict__ hOut,        // enc only: [B][256] bf16
    float* __restrict__ recons)               // dec only: [B][T][4]
{
    extern __shared__ char smem[];
    short* sB = (short*)smem;
    float* cL = (float*)(smem + 65536);
    unsigned short* hL = (unsigned short*)(smem + 98816);
    float* wxL = (float*)(smem + 115712);
    float* bfL = (float*)(smem + 132096);
    float* WcL = (float*)(smem + 136192);
    float* sL  = (float*)(smem + 138240);
    float* redL = (float*)(smem + 138752);

    const int tid = threadIdx.x;
    const int lane = tid & 63;
    const int fr = lane & 15;
    const int kg = lane >> 4;
    const int wave = tid >> 6;
    const int r2 = wave >> 1;       // row-group (16 rows)
    const int c2 = wave & 1;        // col-half of 128-col chunk
    const int rw0 = r2 * 16;
    const int rowBase = blockIdx.x * RB;

    // ---- prologue: init LDS state ----
    #pragma unroll
    for (int j = 0; j < 8; ++j) {                 // cL (32x256 f32, padded rows)
        int idx = tid + j * 256;
        int row = idx >> 6, col = (idx & 63) * 4;
        float4 v;
        if (DEC) v = *(const float4*)(cInit + (size_t)(rowBase + row) * 256 + col);
        else     v = make_float4(0.f, 0.f, 0.f, 0.f);
        *(float4*)(cL + row * 260 + col) = v;
    }
    #pragma unroll
    for (int j = 0; j < 4; ++j) {                 // hL (32x256 bf16, padded rows)
        int c = tid + j * 256;
        int row = c >> 5, seg = c & 31;
        if (DEC) *(float4*)(hL + row * 264 + seg * 8) =
                     *(const float4*)(hInit + (size_t)(rowBase + row) * 256 + seg * 8);
        else {
            float4 z = make_float4(0.f, 0.f, 0.f, 0.f);
            *(float4*)(hL + row * 264 + seg * 8) = z;
        }
    }
    #pragma unroll
    for (int j = 0; j < 4; ++j) {                 // wxL
        int idx = tid + j * 256;
        *(float4*)(wxL + idx * 4) = *(const float4*)(WxP + idx * 4);
    }
    *(float4*)(bfL + tid * 4) = *(const float4*)(bfP + tid * 4);
    if (DEC) {
        if (tid < 128) *(float4*)(WcL + tid * 4) = *(const float4*)(Wc + tid * 4);
        if (tid < RB)  *(float4*)(sL + tid * 4) = *(const float4*)(initS + (size_t)(rowBase + tid) * 4);
    }
    __syncthreads();

    for (int t = 0; t < T_; ++t) {
        // a-fragments for this wave's 16 rows (h_t), from LDS
        short8 afr[8];
        #pragma unroll
        for (int k0 = 0; k0 < 8; ++k0)
            afr[k0] = *(const short8*)(hL + (rw0 + fr) * 264 + (k0 * 4 + kg) * 8);
        // x vectors for this lane's 4 epilogue rows
        float4 xv[4];
        #pragma unroll
        for (int rr = 0; rr < 4; ++rr) {
            int row = rw0 + kg * 4 + rr;
            if (DEC) xv[rr] = *(const float4*)(sL + row * 4);
            else     xv[rr] = *(const float4*)(rel + ((size_t)(rowBase + row) * T_ + t) * 4);
        }
        // issue chunk-0 B loads
        float4 stg[16];
        #pragma unroll
        for (int q = 0; q < 16; ++q) {
            int cid = q * 256 + tid;
            int brow = cid >> 5, slot = cid & 31;
            stg[q] = *(const float4*)(WhP + (size_t)brow * 256 + slot * 8);
        }
        __syncthreads();   // afr/xv reads complete; prior-step sB reads complete

        for (int ci = 0; ci < 8; ++ci) {
            // write staged chunk to sB (XOR-swizzled 16B slots)
            #pragma unroll
            for (int q = 0; q < 16; ++q) {
                int cid = q * 256 + tid;
                int brow = cid >> 5, slot = cid & 31;
                *(float4*)(sB + brow * 256 + (slot ^ (brow & 7)) * 8) = stg[q];
            }
            __syncthreads();   // sB ready
            if (ci < 7) {      // prefetch next chunk into regs (latency hidden by compute)
                #pragma unroll
                for (int q = 0; q < 16; ++q) {
                    int cid = q * 256 + tid;
                    int brow = cid >> 5, slot = cid & 31;
                    stg[q] = *(const float4*)(WhP + (size_t)((ci + 1) * 128 + brow) * 256 + slot * 8);
                }
            }
            // MFMA: 16 rows x 64 cols per wave
            f32x4 acc[4] = {};
            #pragma unroll
            for (int k0 = 0; k0 < 8; ++k0) {
                int kch = k0 * 4 + kg;
                short8 bfrag[4];
                #pragma unroll
                for (int n = 0; n < 4; ++n) {
                    int rb = c2 * 64 + n * 16 + fr;
                    bfrag[n] = *(const short8*)(sB + rb * 256 + ((kch ^ (rb & 7))) * 8);
                }
                #pragma unroll
                for (int n = 0; n < 4; ++n)
                    acc[n] = __builtin_amdgcn_mfma_f32_16x16x32_bf16(afr[k0], bfrag[n], acc[n], 0, 0, 0);
            }
            // epilogue: lane owns unit uloc, gates n=0..3, rows kg*4+rr
            int uloc = ci * 32 + c2 * 16 + fr;
            int npB  = ci * 128 + c2 * 64 + fr;
            float bfv[4], wx0[4], wx1[4], wx2[4], wx3[4];
            #pragma unroll
            for (int n = 0; n < 4; ++n) {
                bfv[n] = bfL[npB + n * 16];
                wx0[n] = wxL[npB + n * 16];
                wx1[n] = wxL[1024 + npB + n * 16];
                wx2[n] = wxL[2048 + npB + n * 16];
                wx3[n] = wxL[3072 + npB + n * 16];
            }
            #pragma unroll
            for (int rr = 0; rr < 4; ++rr) {
                int rl = rw0 + kg * 4 + rr;
                float g0 = acc[0][rr] + bfv[0] + xv[rr].x * wx0[0] + xv[rr].y * wx1[0] + xv[rr].z * wx2[0] + xv[rr].w * wx3[0];
                float g1 = acc[1][rr] + bfv[1] + xv[rr].x * wx0[1] + xv[rr].y * wx1[1] + xv[rr].z * wx2[1] + xv[rr].w * wx3[1];
                float g2 = acc[2][rr] + bfv[2] + xv[rr].x * wx0[2] + xv[rr].y * wx1[2] + xv[rr].z * wx2[2] + xv[rr].w * wx3[2];
                float g3 = acc[3][rr] + bfv[3] + xv[rr].x * wx0[3] + xv[rr].y * wx1[3] + xv[rr].z * wx2[3] + xv[rr].w * wx3[3];
                float cc = cL[rl * 260 + uloc];
                float iv = fast_sigmoid(g0);
                float fv = fast_sigmoid(g1);
                float gv = fast_tanh(g2);
                float ov = fast_sigmoid(g3);
                float cn = fv * cc + iv * gv;
                cL[rl * 260 + uloc] = cn;
                hL[rl * 264 + uloc] = f2bf(ov * fast_tanh(cn));
            }
            __syncthreads();   // sB reads + hL writes done before next chunk / step end
        }

        if (DEC) {
            // ctrl head: per row, 2 dots of length 256 over new h
            int rrow = tid >> 3, part = tid & 7;
            float a0 = 0.f, a1 = 0.f;
            #pragma unroll 8
            for (int i = 0; i < 32; ++i) {
                int u = part * 32 + i;
                float hv = bf2f(hL[rrow * 264 + u]);
                a0 = fmaf(hv, WcL[u * 2], a0);
                a1 = fmaf(hv, WcL[u * 2 + 1], a1);
            }
            redL[(rrow * 8 + part) * 2] = a0;
            redL[(rrow * 8 + part) * 2 + 1] = a1;
            __syncthreads();
            if (tid < RB) {
                float p0 = 0.f, p1 = 0.f;
                #pragma unroll
                for (int p = 0; p < 8; ++p) {
                    p0 += redL[(tid * 8 + p) * 2];
                    p1 += redL[(tid * 8 + p) * 2 + 1];
                }
                float pedal = p0 + bc[0];
                float steer = fminf(fmaxf(p1 + bc[1], -0.5f), 0.5f);
                float4 sv = *(float4*)(sL + tid * 4);
                float v = sv.w;
                float v1 = fminf(fmaxf(v + pedal * DT_, 0.f), 10.f);
                float pd = fminf(fmaxf(v * tanf(steer) * (1.f / 2.5f), -1.57f), 1.57f);
                float4 ns;
                ns.x = sv.x + v1 * cosf(sv.z) * DT_;
                ns.y = sv.y + v1 * sinf(sv.z) * DT_;
                ns.z = sv.z + pd * DT_;
                ns.w = v1;
                *(float4*)(sL + tid * 4) = ns;
                *(float4*)(recons + ((size_t)(rowBase + tid) * T_ + t) * 4) = ns;
            }
            __syncthreads();
        }
    }

    if (!DEC) {   // write final h for the MLPs
        #pragma unroll
        for (int j = 0; j < 4; ++j) {
            int c = tid + j * 256;
            int row = c >> 5, seg = c & 31;
            *(float4*)(hOut + (size_t)(rowBase + row) * 256 + seg * 8) =
                *(float4*)(hL + row * 264 + seg * 8);
        }
    }
}

// ---------- MFMA GEMM for MLP layers (z-batched): C = A@W_z^T + bias_z [; leaky] ----------
__global__ __launch_bounds__(256) void mlp_gemm_kernel(
    const unsigned short* __restrict__ Ain, size_t aZStride,
    const unsigned short* __restrict__ WTb, size_t wZStride,
    const float* __restrict__ b0, const float* __restrict__ b1,
    float* __restrict__ outF, size_t ofZStride,
    unsigned short* __restrict__ outB, size_t obZStride,
    int act)
{
    const int z = blockIdx.z;
    const unsigned short* A  = Ain + (size_t)z * aZStride;
    const unsigned short* WT = WTb + (size_t)z * wZStride;
    const float* bias = z ? b1 : b0;

    __shared__ __align__(16) short sA[64 * 256];
    __shared__ __align__(16) short sBm[64 * 256];
    const int tid = threadIdx.x;
    const int lane = tid & 63;
    const int wr = (tid >> 7) & 1;
    const int wc = (tid >> 6) & 1;
    const int rowBase = blockIdx.x * 64;
    const int nBase = blockIdx.y * 64;

    {
        const unsigned short* gA = A + (size_t)rowBase * 256;
        const unsigned short* gB = WT + (size_t)nBase * 256;
        #pragma unroll
        for (int i = 0; i < 8; ++i) {
            int ch = tid + i * 256;
            int row = ch >> 5, slot = ch & 31;
            float4 va = *(const float4*)(gA + row * 256 + slot * 8);
            float4 vb = *(const float4*)(gB + row * 256 + slot * 8);
            int sl = slot ^ (row & 7);
            *(float4*)(sA + row * 256 + sl * 8) = va;
            *(float4*)(sBm + row * 256 + sl * 8) = vb;
        }
    }
    __syncthreads();

    const int fr = lane & 15;
    const int kg = lane >> 4;
    f32x4 acc[2][2] = {};
    #pragma unroll
    for (int k0 = 0; k0 < 8; ++k0) {
        int kch = k0 * 4 + kg;
        short8 a[2], b[2];
        #pragma unroll
        for (int m = 0; m < 2; ++m) {
            int r = wr * 32 + m * 16 + fr;
            a[m] = *(const short8*)(sA + r * 256 + (kch ^ (r & 7)) * 8);
        }
        #pragma unroll
        for (int n = 0; n < 2; ++n) {
            int r = wc * 32 + n * 16 + fr;
            b[n] = *(const short8*)(sBm + r * 256 + (kch ^ (r & 7)) * 8);
        }
        #pragma unroll
        for (int m = 0; m < 2; ++m)
            #pragma unroll
            for (int n = 0; n < 2; ++n)
                acc[m][n] = __builtin_amdgcn_mfma_f32_16x16x32_bf16(a[m], b[n], acc[m][n], 0, 0, 0);
    }

    #pragma unroll
    for (int m = 0; m < 2; ++m) {
        #pragma unroll
        for (int n = 0; n < 2; ++n) {
            int col = nBase + wc * 32 + n * 16 + fr;
            float bv = bias[col];
            #pragma unroll
            for (int r = 0; r < 4; ++r) {
                int row = rowBase + wr * 32 + m * 16 + kg * 4 + r;
                float v = acc[m][n][r] + bv;
                if (act) v = v > 0.f ? v : 0.01f * v;
                if (outF) outF[(size_t)z * ofZStride + (size_t)row * H_ + col] = v;
                if (outB) outB[(size_t)z * obZStride + (size_t)row * H_ + col] = f2bf(v);
            }
        }
    }
}

// ---------- z = tanh(eps*exp(0.5*lv)+mu) -> bf16 ----------
__global__ void z_kernel(const float* __restrict__ eps, const float* __restrict__ mu,
                         const float* __restrict__ lv, unsigned short* __restrict__ z) {
    int id = blockIdx.x * blockDim.x + threadIdx.x;
    z[id] = f2bf(tanhf(eps[id] * expf(0.5f * lv[id]) + mu[id]));
}

extern "C" void kernel_launch(void* const* d_in, const int* in_sizes, int n_in,
                              void* d_out, int out_size, void* d_ws, size_t ws_size,
                              hipStream_t stream) {
    (void)in_sizes; (void)n_in; (void)out_size; (void)ws_size;
    const float* traj       = (const float*)d_in[0];
    const float* init_s     = (const float*)d_in[1];
    const float* eps        = (const float*)d_in[2];
    const float* enc_emb_W  = (const float*)d_in[3];
    const float* enc_emb_b  = (const float*)d_in[4];
    const float* enc_Wih    = (const float*)d_in[5];
    const float* enc_bih    = (const float*)d_in[6];
    const float* enc_Whh    = (const float*)d_in[7];
    const float* enc_bhh    = (const float*)d_in[8];
    const float* mu_W       = (const float*)d_in[9];
    const float* mu_b       = (const float*)d_in[10];
    const float* lv_W       = (const float*)d_in[11];
    const float* lv_b       = (const float*)d_in[12];
    const float* dec_emb_W  = (const float*)d_in[13];
    const float* dec_emb_b  = (const float*)d_in[14];
    const float* dec_init_W = (const float*)d_in[15];
    const float* dec_init_b = (const float*)d_in[16];
    const float* dec_Wih    = (const float*)d_in[17];
    const float* dec_bih    = (const float*)d_in[18];
    const float* dec_Whh    = (const float*)d_in[19];
    const float* dec_bhh    = (const float*)d_in[20];
    const float* ctrl_W     = (const float*)d_in[21];
    const float* ctrl_b     = (const float*)d_in[22];

    float* out = (float*)d_out;
    float* recons = out;                              // B*T*4
    float* expert = out + (size_t)B_ * T_ * 4;        // B*T*4
    float* mu_out = expert + (size_t)B_ * T_ * 4;     // B*H
    float* lv_out = mu_out + (size_t)B_ * H_;         // B*H  (adjacent -> z-strided store)

    float* ws = (float*)d_ws;
    size_t o = 0;
    float* rel = ws + o;  o += (size_t)B_ * T_ * 4;
    unsigned short* WhPE = (unsigned short*)(ws + o); o += NG_ * H_ / 2;
    unsigned short* WhPD = (unsigned short*)(ws + o); o += NG_ * H_ / 2;
    unsigned short* WT9  = (unsigned short*)(ws + o); o += 9 * H_ * H_ / 2;
    float* WxPE = ws + o; o += 4 * NG_;
    float* WxPD = ws + o; o += 4 * NG_;
    float* bfPE = ws + o; o += NG_;
    float* bfPD = ws + o; o += NG_;
    unsigned short* hEnc = (unsigned short*)(ws + o); o += (size_t)B_ * H_ / 2;
    unsigned short* tbA  = (unsigned short*)(ws + o); o += (size_t)B_ * H_;       // 2 z-slots
    unsigned short* tbB  = (unsigned short*)(ws + o); o += (size_t)B_ * H_;       // 2 z-slots
    float* cInit = ws + o; o += (size_t)B_ * H_;
    unsigned short* hInit = (unsigned short*)(ws + o); o += (size_t)B_ * H_ / 2;

    // allow >64KB dynamic LDS for the persistent kernels
    hipFuncSetAttribute((const void*)lstm_persist_kernel<0>,
                        hipFuncAttributeMaxDynamicSharedMemorySize, SMEM_BYTES);
    hipFuncSetAttribute((const void*)lstm_persist_kernel<1>,
                        hipFuncAttributeMaxDynamicSharedMemorySize, SMEM_BYTES);

    // ---- prep ----
    fold_perm_kernel<<<80, 256, 0, stream>>>(enc_emb_W, enc_emb_b, enc_Wih, enc_bih, enc_bhh, WxPE, bfPE);
    fold_perm_kernel<<<80, 256, 0, stream>>>(dec_emb_W, dec_emb_b, dec_Wih, dec_bih, dec_bhh, WxPD, bfPD);
    prep_whp_kernel<<<1024, 256, 0, stream>>>(enc_Whh, WhPE);
    prep_whp_kernel<<<1024, 256, 0, stream>>>(dec_Whh, WhPD);
    prep_wt_all_kernel<<<dim3(256, 9), 256, 0, stream>>>(mu_W, lv_W, dec_init_W, WT9);
    rel_kernel<<<(B_ * T_ + 255) / 256, 256, 0, stream>>>(traj, rel, (float4*)expert);

    // ---- encoder (one persistent launch) ----
    lstm_persist_kernel<0><<<NBLK, 256, SMEM_BYTES, stream>>>(
        rel, WhPE, WxPE, bfPE, nullptr, nullptr, nullptr, nullptr, nullptr, hEnc, nullptr);

    // ---- mu/lv MLPs, z-batched ----
    dim3 gridM2(B_ / 64, H_ / 64, 2);
    size_t BH = (size_t)B_ * H_;
    mlp_gemm_kernel<<<gridM2, 256, 0, stream>>>(hEnc, 0, WT9 + 0 * 65536, (size_t)4 * 65536,
                                                mu_b + 0,   lv_b + 0,   nullptr, 0, tbA, BH / 2, 1);
    mlp_gemm_kernel<<<gridM2, 256, 0, stream>>>(tbA, BH / 2, WT9 + 1 * 65536, (size_t)4 * 65536,
                                                mu_b + 256, lv_b + 256, nullptr, 0, tbB, BH / 2, 1);
    mlp_gemm_kernel<<<gridM2, 256, 0, stream>>>(tbB, BH / 2, WT9 + 2 * 65536, (size_t)4 * 65536,
                                                mu_b + 512, lv_b + 512, nullptr, 0, tbA, BH / 2, 1);
    mlp_gemm_kernel<<<gridM2, 256, 0, stream>>>(tbA, BH / 2, WT9 + 3 * 65536, (size_t)4 * 65536,
                                                mu_b + 768, lv_b + 768, mu_out, BH / 2, nullptr, 0, 1);

    // ---- z, decoder init ----
    z_kernel<<<B_ * H_ / 256, 256, 0, stream>>>(eps, mu_out, lv_out, tbB);
    dim3 gridM1(B_ / 64, H_ / 64, 1);
    mlp_gemm_kernel<<<gridM1, 256, 0, stream>>>(tbB, 0, WT9 + 8 * 65536, 0,
                                                dec_init_b, dec_init_b, cInit, 0, hInit, 0, 0);

    // ---- decoder (one persistent launch) ----
    lstm_persist_kernel<1><<<NBLK, 256, SMEM_BYTES, stream>>>(
        nullptr, WhPD, WxPD, bfPD, cInit, hInit, init_s, ctrl_W, ctrl_b, nullptr, recons);
}

// Round 4
// 1375.087 us; speedup vs baseline: 2.3707x; 2.3707x over previous
//
#include <hip/hip_runtime.h>
#include <math.h>

#define B_ 8192
#define T_ 30
#define H_ 256
#define NG_ 1024
#define DT_ 0.03f
#define RB 32
#define NBLK (B_ / RB)   // 256

typedef __attribute__((ext_vector_type(8))) short short8;
typedef __attribute__((ext_vector_type(4))) float f32x4;

__device__ inline float bf2f(unsigned short u) {
    unsigned int x = ((unsigned int)u) << 16;
    return __builtin_bit_cast(float, x);
}
__device__ inline unsigned short f2bf(float f) {
    unsigned int x = __builtin_bit_cast(unsigned int, f);
    return (unsigned short)((x + 0x7FFF + ((x >> 16) & 1)) >> 16);
}
__device__ inline float fast_tanh(float x) {
    float e = __expf(2.f * x);
    return 1.f - 2.f / (e + 1.f);
}
__device__ inline float fast_sigmoid(float x) {
    return 1.f / (1.f + __expf(-x));
}
__device__ inline void gl16(const unsigned short* g, unsigned short* l) {
    __builtin_amdgcn_global_load_lds((const __attribute__((address_space(1))) void*)g,
                                     (__attribute__((address_space(3))) void*)l, 16, 0, 0);
}

// ---------- fused fold+permute: WxP[r][n'] = (W1@W2)[r][co(n')], bfP[n'] = (b1@W2+bih+bhh)[co] ----------
// n' = bN*64 + g*16 + j  <->  co = g*256 + bN*16 + j
__global__ void fold_perm_kernel(const float* __restrict__ W1, const float* __restrict__ b1,
                                 const float* __restrict__ W2,
                                 const float* __restrict__ bih, const float* __restrict__ bhh,
                                 float* __restrict__ WxP, float* __restrict__ bfP) {
    __shared__ float sP[4][64];
    const int t63 = threadIdx.x & 63;
    const int kc = threadIdx.x >> 6;
    int o = blockIdx.x * 64 + t63;          // 0..5119 (r=4 is bias row)
    int r = o >> 10;
    int np = o & 1023;
    int bN = np >> 6, g = (np >> 4) & 3, j = np & 15;
    int co = g * 256 + bN * 16 + j;
    const float* w1row = (r < 4) ? (W1 + r * 128) : b1;
    float acc = 0.f;
    #pragma unroll 8
    for (int k = kc * 32; k < kc * 32 + 32; ++k)
        acc = fmaf(w1row[k], W2[k * NG_ + co], acc);
    sP[kc][t63] = acc;
    __syncthreads();
    if (kc == 0) {
        acc = sP[0][t63] + sP[1][t63] + sP[2][t63] + sP[3][t63];
        if (r < 4) WxP[r * NG_ + np] = acc;
        else       bfP[np] = acc + bih[co] + bhh[co];
    }
}

// WhP_sw: permuted + BANK-SWIZZLE BAKED IN. Element (gatecol np, k) stored at
// np*256 + ((k>>3)^(np&7))*8 + (k&7)  -- so a linear global->LDS copy yields the swizzled tile.
__global__ void prep_whp_kernel(const float* __restrict__ W, unsigned short* __restrict__ WhP) {
    int id = blockIdx.x * blockDim.x + threadIdx.x;  // 1024*256
    int np = id >> 8, k = id & 255;
    int bN = np >> 6, g = (np >> 4) & 3, j = np & 15;
    int co = g * 256 + bN * 16 + j;
    int dst = np * 256 + ((((k >> 3) ^ (np & 7))) << 3) + (k & 7);
    WhP[dst] = f2bf(W[(size_t)k * NG_ + co]);
}

// WT[m][n][k] = bf16(W_m[k][n]) for 9 matrices (mu0..3, lv0..3, dec_init)
__global__ void prep_wt_all_kernel(const float* __restrict__ muW, const float* __restrict__ lvW,
                                   const float* __restrict__ diW, unsigned short* __restrict__ WT9) {
    int m = blockIdx.y;
    const float* src = (m < 4) ? muW + (size_t)m * 65536
                     : (m < 8) ? lvW + (size_t)(m - 4) * 65536
                               : diW;
    int id = blockIdx.x * 256 + threadIdx.x;
    int n = id >> 8, k = id & 255;
    WT9[(size_t)m * 65536 + id] = f2bf(src[k * H_ + n]);
}

// ---------- rel input + expert passthrough ----------
__global__ void rel_kernel(const float* __restrict__ traj, float* __restrict__ rel,
                           float4* __restrict__ expert) {
    int id = blockIdx.x * blockDim.x + threadIdx.x;
    if (id >= B_ * T_) return;
    int t = id % T_;
    const float* p = traj + (size_t)id * 4;
    float x = p[0], y = p[1];
    if (t > 0) { x -= p[-4]; y -= p[-3]; }
    float* o = rel + (size_t)id * 4;
    o[0] = x; o[1] = y; o[2] = p[2]; o[3] = p[3];
    expert[id] = ((const float4*)traj)[id];
}

// ---------- persistent LSTM v2 ----------
// LDS: buf0 0..65536 | buf1 ..131072 | hL[32][264]bf16 ..147968 | wx[4][1024]bf16 ..156160
//      bf[1024]f32 ..160256 | Wc[512]f32 ..162304 | sL[128]f32 ..162816 | red[128]f32 ..163328
#define SMEM2 163328

template <int DEC>
__global__ __launch_bounds__(256, 1) void lstm_persist2_kernel(
    const float* __restrict__ rel,            // enc: [B][T][4]
    const unsigned short* __restrict__ WhP,   // [1024][256] bf16 permuted+swizzled
    const float* __restrict__ WxP,            // [4][1024]
    const float* __restrict__ bfP,            // [1024]
    const float* __restrict__ cInit,          // dec: [B][256] f32 (natural unit order)
    const unsigned short* __restrict__ hInit, // dec: [B][256] bf16
    const float* __restrict__ initS,          // dec: [B][4]
    const float* __restrict__ Wc,             // dec: [256][2]
    const float* __restrict__ bc,             // dec: [2]
    unsigned short* __restrict__ hOut,        // enc: [B][256] bf16
    float* __restrict__ recons)               // dec: [B][T][4]
{
    extern __shared__ char smem[];
    unsigned short* bufA = (unsigned short*)smem;
    unsigned short* bufB = (unsigned short*)(smem + 65536);
    unsigned short* hLp  = (unsigned short*)(smem + 131072);
    unsigned short* wxLp = (unsigned short*)(smem + 147968);
    float* bfLp  = (float*)(smem + 156160);
    float* WcLp  = (float*)(smem + 160256);
    float* sLp   = (float*)(smem + 162304);
    float* redLp = (float*)(smem + 162816);

    const int tid = threadIdx.x;
    const int lane = tid & 63;
    const int fr = lane & 15;
    const int kg = lane >> 4;
    const int wave = tid >> 6;
    const int r2 = wave >> 1;
    const int c2 = wave & 1;
    const int rw0 = r2 * 16;
    const int rowBase = blockIdx.x * RB;

    // ---- prologue ----
    if (DEC) {
        #pragma unroll
        for (int g = 0; g < 4; ++g) {
            int idx = tid + g * 256;                 // 1024 groups of 8 shorts
            int row = idx >> 5, seg = idx & 31;
            *(short8*)(hLp + row * 264 + seg * 8) =
                *(const short8*)(hInit + (size_t)(rowBase + row) * 256 + seg * 8);
        }
        if (tid < 128) *(float4*)(WcLp + tid * 4) = *(const float4*)(Wc + tid * 4);
        if (tid < RB)  *(float4*)(sLp + tid * 4) = *(const float4*)(initS + (size_t)(rowBase + tid) * 4);
    } else {
        for (int i = tid; i < 32 * 264; i += 256) hLp[i] = 0;
    }
    for (int i = tid; i < 4096; i += 256) wxLp[i] = f2bf(WxP[i]);
    for (int i = tid; i < 1024; i += 256) bfLp[i] = bfP[i];
    float bc0 = 0.f, bc1 = 0.f;
    if (DEC) { bc0 = bc[0]; bc1 = bc[1]; }

    float cReg[32];
    #pragma unroll
    for (int ci = 0; ci < 8; ++ci)
        #pragma unroll
        for (int rr = 0; rr < 4; ++rr) {
            if (DEC) cReg[ci * 4 + rr] =
                cInit[(size_t)(rowBase + rw0 + kg * 4 + rr) * 256 + ci * 32 + c2 * 16 + fr];
            else cReg[ci * 4 + rr] = 0.f;
        }

    // stage chunks 0,1 (16 x 16B per thread per chunk; linear; swizzle is baked in source)
    {
        const unsigned short* g0 = WhP + 0 * 32768 + wave * 8192 + lane * 8;
        const unsigned short* g1 = WhP + 1 * 32768 + wave * 8192 + lane * 8;
        unsigned short* l0 = bufA + wave * 8192;
        unsigned short* l1 = bufB + wave * 8192;
        #pragma unroll
        for (int q = 0; q < 16; ++q) gl16(g0 + q * 512, l0 + q * 512);
        #pragma unroll
        for (int q = 0; q < 16; ++q) gl16(g1 + q * 512, l1 + q * 512);
    }

    float hCtrl[32];

    for (int t = 0; t < T_; ++t) {
        // step start: all prior LDS writes (h, sL, prologue) visible
        asm volatile("s_waitcnt lgkmcnt(0)" ::: "memory");
        __builtin_amdgcn_s_barrier();
        __builtin_amdgcn_sched_barrier(0);

        short8 afr[8];
        #pragma unroll
        for (int k0 = 0; k0 < 8; ++k0)
            afr[k0] = *(const short8*)(hLp + (rw0 + fr) * 264 + (k0 * 4 + kg) * 8);
        float4 xv[4];
        #pragma unroll
        for (int rr = 0; rr < 4; ++rr) {
            int row = rw0 + kg * 4 + rr;
            if (DEC) xv[rr] = *(const float4*)(sLp + row * 4);
            else     xv[rr] = *(const float4*)(rel + ((size_t)(rowBase + row) * T_ + t) * 4);
        }
        // drain stray VMEM (enc xv etc). Staged chunks 0,1 were issued >=2 chunk-periods ago.
        asm volatile("s_waitcnt vmcnt(0)" ::: "memory");

        #pragma unroll
        for (int ci = 0; ci < 8; ++ci) {
            unsigned short* buf = (ci & 1) ? bufB : bufA;
            // chunk ci staged (16 newest outstanding = chunk ci+1)
            asm volatile("s_waitcnt vmcnt(16)" ::: "memory");
            __builtin_amdgcn_s_barrier();
            __builtin_amdgcn_sched_barrier(0);

            f32x4 acc[4] = {f32x4{0.f,0.f,0.f,0.f}, f32x4{0.f,0.f,0.f,0.f},
                            f32x4{0.f,0.f,0.f,0.f}, f32x4{0.f,0.f,0.f,0.f}};
            #pragma unroll
            for (int k0 = 0; k0 < 8; ++k0) {
                int kch = k0 * 4 + kg;
                short8 b0, b1, b2, b3;
                {
                    int rb = c2 * 64 + 0 * 16 + fr;
                    b0 = *(const short8*)(buf + rb * 256 + ((kch ^ (rb & 7)) << 3));
                    rb = c2 * 64 + 1 * 16 + fr;
                    b1 = *(const short8*)(buf + rb * 256 + ((kch ^ (rb & 7)) << 3));
                    rb = c2 * 64 + 2 * 16 + fr;
                    b2 = *(const short8*)(buf + rb * 256 + ((kch ^ (rb & 7)) << 3));
                    rb = c2 * 64 + 3 * 16 + fr;
                    b3 = *(const short8*)(buf + rb * 256 + ((kch ^ (rb & 7)) << 3));
                }
                acc[0] = __builtin_amdgcn_mfma_f32_16x16x32_bf16(afr[k0], b0, acc[0], 0, 0, 0);
                acc[1] = __builtin_amdgcn_mfma_f32_16x16x32_bf16(afr[k0], b1, acc[1], 0, 0, 0);
                acc[2] = __builtin_amdgcn_mfma_f32_16x16x32_bf16(afr[k0], b2, acc[2], 0, 0, 0);
                acc[3] = __builtin_amdgcn_mfma_f32_16x16x32_bf16(afr[k0], b3, acc[3], 0, 0, 0);
            }
            asm volatile("s_waitcnt lgkmcnt(0)" ::: "memory");
            __builtin_amdgcn_sched_barrier(0);
            __builtin_amdgcn_s_barrier();   // all waves' reads of buf done -> safe to overwrite
            if (!(t == T_ - 1 && ci >= 6)) {
                int cn = (ci + 2) & 7;
                const unsigned short* g = WhP + (size_t)cn * 32768 + wave * 8192 + lane * 8;
                unsigned short* l = buf + wave * 8192;
                #pragma unroll
                for (int q = 0; q < 16; ++q) gl16(g + q * 512, l + q * 512);
            }

            // epilogue: lane owns unit uloc = ci*32+c2*16+fr (4 gates = acc[0..3]), rows kg*4+rr
            const int npB = ci * 128 + c2 * 64 + fr;
            const int uloc = ci * 32 + c2 * 16 + fr;
            float bfv[4], wxv[4][4];
            #pragma unroll
            for (int n = 0; n < 4; ++n) bfv[n] = bfLp[npB + n * 16];
            #pragma unroll
            for (int k = 0; k < 4; ++k)
                #pragma unroll
                for (int n = 0; n < 4; ++n)
                    wxv[k][n] = bf2f(wxLp[k * 1024 + npB + n * 16]);
            #pragma unroll
            for (int rr = 0; rr < 4; ++rr) {
                float xvk[4] = {xv[rr].x, xv[rr].y, xv[rr].z, xv[rr].w};
                float g0 = acc[0][rr] + bfv[0], g1 = acc[1][rr] + bfv[1];
                float g2 = acc[2][rr] + bfv[2], g3 = acc[3][rr] + bfv[3];
                #pragma unroll
                for (int k = 0; k < 4; ++k) {
                    g0 = fmaf(xvk[k], wxv[k][0], g0);
                    g1 = fmaf(xvk[k], wxv[k][1], g1);
                    g2 = fmaf(xvk[k], wxv[k][2], g2);
                    g3 = fmaf(xvk[k], wxv[k][3], g3);
                }
                float iv = fast_sigmoid(g0);
                float fv = fast_sigmoid(g1);
                float gv = fast_tanh(g2);
                float ov = fast_sigmoid(g3);
                float cn2 = fv * cReg[ci * 4 + rr] + iv * gv;
                cReg[ci * 4 + rr] = cn2;
                float hval = ov * fast_tanh(cn2);
                if (DEC) hCtrl[ci * 4 + rr] = hval;
                hLp[(rw0 + kg * 4 + rr) * 264 + uloc] = f2bf(hval);
            }
        }

        if (DEC) {
            // ctrl head from fp32 h in registers
            float p0[4] = {0.f, 0.f, 0.f, 0.f}, p1[4] = {0.f, 0.f, 0.f, 0.f};
            #pragma unroll
            for (int ci = 0; ci < 8; ++ci) {
                int u = ci * 32 + c2 * 16 + fr;
                float w0 = WcLp[u * 2], w1 = WcLp[u * 2 + 1];
                #pragma unroll
                for (int rr = 0; rr < 4; ++rr) {
                    p0[rr] = fmaf(hCtrl[ci * 4 + rr], w0, p0[rr]);
                    p1[rr] = fmaf(hCtrl[ci * 4 + rr], w1, p1[rr]);
                }
            }
            #pragma unroll
            for (int m = 1; m < 16; m <<= 1) {
                #pragma unroll
                for (int rr = 0; rr < 4; ++rr) {
                    p0[rr] += __shfl_xor(p0[rr], m);
                    p1[rr] += __shfl_xor(p1[rr], m);
                }
            }
            if (fr == 0) {
                #pragma unroll
                for (int rr = 0; rr < 4; ++rr) {
                    int row = rw0 + kg * 4 + rr;
                    redLp[row * 4 + c2 * 2 + 0] = p0[rr];
                    redLp[row * 4 + c2 * 2 + 1] = p1[rr];
                }
            }
            asm volatile("s_waitcnt lgkmcnt(0)" ::: "memory");
            __builtin_amdgcn_s_barrier();
            if (tid < RB) {
                float pedal = redLp[tid * 4 + 0] + redLp[tid * 4 + 2] + bc0;
                float steer = fminf(fmaxf(redLp[tid * 4 + 1] + redLp[tid * 4 + 3] + bc1, -0.5f), 0.5f);
                float4 sv = *(float4*)(sLp + tid * 4);
                float v = sv.w;
                float v1 = fminf(fmaxf(v + pedal * DT_, 0.f), 10.f);
                float pd = fminf(fmaxf(v * tanf(steer) * (1.f / 2.5f), -1.57f), 1.57f);
                float4 ns;
                ns.x = sv.x + v1 * cosf(sv.z) * DT_;
                ns.y = sv.y + v1 * sinf(sv.z) * DT_;
                ns.z = sv.z + pd * DT_;
                ns.w = v1;
                *(float4*)(sLp + tid * 4) = ns;
                *(float4*)(recons + ((size_t)(rowBase + tid) * T_ + t) * 4) = ns;
            }
        }
    }

    if (!DEC) {
        asm volatile("s_waitcnt lgkmcnt(0)" ::: "memory");
        __builtin_amdgcn_s_barrier();
        #pragma unroll
        for (int g = 0; g < 4; ++g) {
            int idx = tid + g * 256;
            int row = idx >> 5, seg = idx & 31;
            *(short8*)(hOut + (size_t)(rowBase + row) * 256 + seg * 8) =
                *(const short8*)(hLp + row * 264 + seg * 8);
        }
    }
}

// ---------- MFMA GEMM for MLP layers (z-batched) ----------
__global__ __launch_bounds__(256) void mlp_gemm_kernel(
    const unsigned short* __restrict__ Ain, size_t aZStride,
    const unsigned short* __restrict__ WTb, size_t wZStride,
    const float* __restrict__ b0, const float* __restrict__ b1,
    float* __restrict__ outF, size_t ofZStride,
    unsigned short* __restrict__ outB, size_t obZStride,
    int act)
{
    const int z = blockIdx.z;
    const unsigned short* A  = Ain + (size_t)z * aZStride;
    const unsigned short* WT = WTb + (size_t)z * wZStride;
    const float* bias = z ? b1 : b0;

    __shared__ __align__(16) short sA[64 * 256];
    __shared__ __align__(16) short sBm[64 * 256];
    const int tid = threadIdx.x;
    const int lane = tid & 63;
    const int wr = (tid >> 7) & 1;
    const int wc = (tid >> 6) & 1;
    const int rowBase = blockIdx.x * 64;
    const int nBase = blockIdx.y * 64;

    {
        const unsigned short* gA = A + (size_t)rowBase * 256;
        const unsigned short* gB = WT + (size_t)nBase * 256;
        #pragma unroll
        for (int i = 0; i < 8; ++i) {
            int ch = tid + i * 256;
            int row = ch >> 5, slot = ch & 31;
            float4 va = *(const float4*)(gA + row * 256 + slot * 8);
            float4 vb = *(const float4*)(gB + row * 256 + slot * 8);
            int sl = slot ^ (row & 7);
            *(float4*)(sA + row * 256 + sl * 8) = va;
            *(float4*)(sBm + row * 256 + sl * 8) = vb;
        }
    }
    __syncthreads();

    const int fr = lane & 15;
    const int kg = lane >> 4;
    f32x4 acc[2][2] = {};
    #pragma unroll
    for (int k0 = 0; k0 < 8; ++k0) {
        int kch = k0 * 4 + kg;
        short8 a[2], b[2];
        #pragma unroll
        for (int m = 0; m < 2; ++m) {
            int r = wr * 32 + m * 16 + fr;
            a[m] = *(const short8*)(sA + r * 256 + (kch ^ (r & 7)) * 8);
        }
        #pragma unroll
        for (int n = 0; n < 2; ++n) {
            int r = wc * 32 + n * 16 + fr;
            b[n] = *(const short8*)(sBm + r * 256 + (kch ^ (r & 7)) * 8);
        }
        #pragma unroll
        for (int m = 0; m < 2; ++m)
            #pragma unroll
            for (int n = 0; n < 2; ++n)
                acc[m][n] = __builtin_amdgcn_mfma_f32_16x16x32_bf16(a[m], b[n], acc[m][n], 0, 0, 0);
    }

    #pragma unroll
    for (int m = 0; m < 2; ++m) {
        #pragma unroll
        for (int n = 0; n < 2; ++n) {
            int col = nBase + wc * 32 + n * 16 + fr;
            float bv = bias[col];
            #pragma unroll
            for (int r = 0; r < 4; ++r) {
                int row = rowBase + wr * 32 + m * 16 + kg * 4 + r;
                float v = acc[m][n][r] + bv;
                if (act) v = v > 0.f ? v : 0.01f * v;
                if (outF) outF[(size_t)z * ofZStride + (size_t)row * H_ + col] = v;
                if (outB) outB[(size_t)z * obZStride + (size_t)row * H_ + col] = f2bf(v);
            }
        }
    }
}

// ---------- z = tanh(eps*exp(0.5*lv)+mu) -> bf16 ----------
__global__ void z_kernel(const float* __restrict__ eps, const float* __restrict__ mu,
                         const float* __restrict__ lv, unsigned short* __restrict__ z) {
    int id = blockIdx.x * blockDim.x + threadIdx.x;
    z[id] = f2bf(tanhf(eps[id] * expf(0.5f * lv[id]) + mu[id]));
}

extern "C" void kernel_launch(void* const* d_in, const int* in_sizes, int n_in,
                              void* d_out, int out_size, void* d_ws, size_t ws_size,
                              hipStream_t stream) {
    (void)in_sizes; (void)n_in; (void)out_size; (void)ws_size;
    const float* traj       = (const float*)d_in[0];
    const float* init_s     = (const float*)d_in[1];
    const float* eps        = (const float*)d_in[2];
    const float* enc_emb_W  = (const float*)d_in[3];
    const float* enc_emb_b  = (const float*)d_in[4];
    const float* enc_Wih    = (const float*)d_in[5];
    const float* enc_bih    = (const float*)d_in[6];
    const float* enc_Whh    = (const float*)d_in[7];
    const float* enc_bhh    = (const float*)d_in[8];
    const float* mu_W       = (const float*)d_in[9];
    const float* mu_b       = (const float*)d_in[10];
    const float* lv_W       = (const float*)d_in[11];
    const float* lv_b       = (const float*)d_in[12];
    const float* dec_emb_W  = (const float*)d_in[13];
    const float* dec_emb_b  = (const float*)d_in[14];
    const float* dec_init_W = (const float*)d_in[15];
    const float* dec_init_b = (const float*)d_in[16];
    const float* dec_Wih    = (const float*)d_in[17];
    const float* dec_bih    = (const float*)d_in[18];
    const float* dec_Whh    = (const float*)d_in[19];
    const float* dec_bhh    = (const float*)d_in[20];
    const float* ctrl_W     = (const float*)d_in[21];
    const float* ctrl_b     = (const float*)d_in[22];

    float* out = (float*)d_out;
    float* recons = out;                              // B*T*4
    float* expert = out + (size_t)B_ * T_ * 4;        // B*T*4
    float* mu_out = expert + (size_t)B_ * T_ * 4;     // B*H
    float* lv_out = mu_out + (size_t)B_ * H_;         // B*H

    float* ws = (float*)d_ws;
    size_t o = 0;
    float* rel = ws + o;  o += (size_t)B_ * T_ * 4;
    unsigned short* WhPE = (unsigned short*)(ws + o); o += NG_ * H_ / 2;
    unsigned short* WhPD = (unsigned short*)(ws + o); o += NG_ * H_ / 2;
    unsigned short* WT9  = (unsigned short*)(ws + o); o += 9 * H_ * H_ / 2;
    float* WxPE = ws + o; o += 4 * NG_;
    float* WxPD = ws + o; o += 4 * NG_;
    float* bfPE = ws + o; o += NG_;
    float* bfPD = ws + o; o += NG_;
    unsigned short* hEnc = (unsigned short*)(ws + o); o += (size_t)B_ * H_ / 2;
    unsigned short* tbA  = (unsigned short*)(ws + o); o += (size_t)B_ * H_;  // 2 z-slots
    unsigned short* tbB  = (unsigned short*)(ws + o); o += (size_t)B_ * H_;  // 2 z-slots
    float* cInit = ws + o; o += (size_t)B_ * H_;
    unsigned short* hInit = (unsigned short*)(ws + o); o += (size_t)B_ * H_ / 2;

    hipFuncSetAttribute((const void*)lstm_persist2_kernel<0>,
                        hipFuncAttributeMaxDynamicSharedMemorySize, SMEM2);
    hipFuncSetAttribute((const void*)lstm_persist2_kernel<1>,
                        hipFuncAttributeMaxDynamicSharedMemorySize, SMEM2);

    // ---- prep ----
    fold_perm_kernel<<<80, 256, 0, stream>>>(enc_emb_W, enc_emb_b, enc_Wih, enc_bih, enc_bhh, WxPE, bfPE);
    fold_perm_kernel<<<80, 256, 0, stream>>>(dec_emb_W, dec_emb_b, dec_Wih, dec_bih, dec_bhh, WxPD, bfPD);
    prep_whp_kernel<<<1024, 256, 0, stream>>>(enc_Whh, WhPE);
    prep_whp_kernel<<<1024, 256, 0, stream>>>(dec_Whh, WhPD);
    prep_wt_all_kernel<<<dim3(256, 9), 256, 0, stream>>>(mu_W, lv_W, dec_init_W, WT9);
    rel_kernel<<<(B_ * T_ + 255) / 256, 256, 0, stream>>>(traj, rel, (float4*)expert);

    // ---- encoder (one persistent launch) ----
    lstm_persist2_kernel<0><<<NBLK, 256, SMEM2, stream>>>(
        rel, WhPE, WxPE, bfPE, nullptr, nullptr, nullptr, nullptr, nullptr, hEnc, nullptr);

    // ---- mu/lv MLPs, z-batched (stride = B*H elements — R3 stride bug fixed) ----
    dim3 gridM2(B_ / 64, H_ / 64, 2);
    size_t BH = (size_t)B_ * H_;
    mlp_gemm_kernel<<<gridM2, 256, 0, stream>>>(hEnc, 0, WT9 + 0 * 65536, (size_t)4 * 65536,
                                                mu_b + 0,   lv_b + 0,   nullptr, 0, tbA, BH, 1);
    mlp_gemm_kernel<<<gridM2, 256, 0, stream>>>(tbA, BH, WT9 + 1 * 65536, (size_t)4 * 65536,
                                                mu_b + 256, lv_b + 256, nullptr, 0, tbB, BH, 1);
    mlp_gemm_kernel<<<gridM2, 256, 0, stream>>>(tbB, BH, WT9 + 2 * 65536, (size_t)4 * 65536,
                                                mu_b + 512, lv_b + 512, nullptr, 0, tbA, BH, 1);
    mlp_gemm_kernel<<<gridM2, 256, 0, stream>>>(tbA, BH, WT9 + 3 * 65536, (size_t)4 * 65536,
                                                mu_b + 768, lv_b + 768, mu_out, BH, nullptr, 0, 1);

    // ---- z, decoder init ----
    z_kernel<<<B_ * H_ / 256, 256, 0, stream>>>(eps, mu_out, lv_out, tbB);
    dim3 gridM1(B_ / 64, H_ / 64, 1);
    mlp_gemm_kernel<<<gridM1, 256, 0, stream>>>(tbB, 0, WT9 + 8 * 65536, 0,
                                                dec_init_b, dec_init_b, cInit, 0, hInit, 0, 0);

    // ---- decoder (one persistent launch) ----
    lstm_persist2_kernel<1><<<NBLK, 256, SMEM2, stream>>>(
        nullptr, WhPD, WxPD, bfPD, cInit, hInit, init_s, ctrl_W, ctrl_b, nullptr, recons);
}

// Round 5
// 1205.632 us; speedup vs baseline: 2.7039x; 1.1406x over previous
//
#include <hip/hip_runtime.h>
#include <math.h>

#define B_ 8192
#define T_ 30
#define H_ 256
#define NG_ 1024
#define DT_ 0.03f
#define RB 32
#define NBLK (B_ / RB)   // 256

typedef __attribute__((ext_vector_type(8))) short short8;
typedef __attribute__((ext_vector_type(4))) float f32x4;

__device__ inline float bf2f(unsigned short u) {
    unsigned int x = ((unsigned int)u) << 16;
    return __builtin_bit_cast(float, x);
}
__device__ inline unsigned short f2bf(float f) {
    unsigned int x = __builtin_bit_cast(unsigned int, f);
    return (unsigned short)((x + 0x7FFF + ((x >> 16) & 1)) >> 16);
}
__device__ inline float fast_tanh(float x) {
    float e = __expf(2.f * x);
    return 1.f - 2.f / (e + 1.f);
}
__device__ inline float fast_sigmoid(float x) {
    return 1.f / (1.f + __expf(-x));
}

// ---------- fused fold+permute: WxP[r][n'] = (W1@W2)[r][co(n')], bfP[n'] = (b1@W2+bih+bhh)[co] ----------
// n' = bN*64 + g*16 + j  <->  co = g*256 + bN*16 + j
__global__ void fold_perm_kernel(const float* __restrict__ W1, const float* __restrict__ b1,
                                 const float* __restrict__ W2,
                                 const float* __restrict__ bih, const float* __restrict__ bhh,
                                 float* __restrict__ WxP, float* __restrict__ bfP) {
    __shared__ float sP[4][64];
    const int t63 = threadIdx.x & 63;
    const int kc = threadIdx.x >> 6;
    int o = blockIdx.x * 64 + t63;          // 0..5119 (r=4 is bias row)
    int r = o >> 10;
    int np = o & 1023;
    int bN = np >> 6, g = (np >> 4) & 3, j = np & 15;
    int co = g * 256 + bN * 16 + j;
    const float* w1row = (r < 4) ? (W1 + r * 128) : b1;
    float acc = 0.f;
    #pragma unroll 8
    for (int k = kc * 32; k < kc * 32 + 32; ++k)
        acc = fmaf(w1row[k], W2[k * NG_ + co], acc);
    sP[kc][t63] = acc;
    __syncthreads();
    if (kc == 0) {
        acc = sP[0][t63] + sP[1][t63] + sP[2][t63] + sP[3][t63];
        if (r < 4) WxP[r * NG_ + np] = acc;
        else       bfP[np] = acc + bih[co] + bhh[co];
    }
}

// Packed B for direct L2->VGPR fragment loads:
// Wpk[ colgrp*4096 + k0*512 + kg*128 + fr*8 + e ] = bf16( Whh[k0*32+kg*8+e][ co(colgrp*16+fr) ] )
// so a wave's load at (colgrp,k0) with per-lane offset lane*8 shorts is 1KB contiguous.
__global__ void prep_pack_kernel(const float* __restrict__ W, unsigned short* __restrict__ Wpk) {
    int id = blockIdx.x * blockDim.x + threadIdx.x;  // 1024*256
    int np = id >> 8, k = id & 255;
    int bN = np >> 6, g = (np >> 4) & 3, j = np & 15;
    int co = g * 256 + bN * 16 + j;
    int colgrp = np >> 4, fr = np & 15;
    int k0 = k >> 5, kg = (k >> 3) & 3, e = k & 7;
    Wpk[colgrp * 4096 + k0 * 512 + kg * 128 + fr * 8 + e] = f2bf(W[(size_t)k * NG_ + co]);
}

// WT[m][n][k] = bf16(W_m[k][n]) for 9 matrices (mu0..3, lv0..3, dec_init)
__global__ void prep_wt_all_kernel(const float* __restrict__ muW, const float* __restrict__ lvW,
                                   const float* __restrict__ diW, unsigned short* __restrict__ WT9) {
    int m = blockIdx.y;
    const float* src = (m < 4) ? muW + (size_t)m * 65536
                     : (m < 8) ? lvW + (size_t)(m - 4) * 65536
                               : diW;
    int id = blockIdx.x * 256 + threadIdx.x;
    int n = id >> 8, k = id & 255;
    WT9[(size_t)m * 65536 + id] = f2bf(src[k * H_ + n]);
}

// ---------- rel input + expert passthrough ----------
__global__ void rel_kernel(const float* __restrict__ traj, float* __restrict__ rel,
                           float4* __restrict__ expert) {
    int id = blockIdx.x * blockDim.x + threadIdx.x;
    if (id >= B_ * T_) return;
    int t = id % T_;
    const float* p = traj + (size_t)id * 4;
    float x = p[0], y = p[1];
    if (t > 0) { x -= p[-4]; y -= p[-3]; }
    float* o = rel + (size_t)id * 4;
    o[0] = x; o[1] = y; o[2] = p[2]; o[3] = p[3];
    expert[id] = ((const float4*)traj)[id];
}

// ---------- persistent LSTM v3: 8 waves, B direct from L2, 1-2 barriers/step ----------
template <int DEC>
__global__ __launch_bounds__(512, 2) void lstm_persist3_kernel(
    const float* __restrict__ rel,            // enc: [B][T][4]
    const unsigned short* __restrict__ Wpk,   // packed weights (see prep_pack)
    const float* __restrict__ WxP,            // [4][1024] permuted
    const float* __restrict__ bfP,            // [1024] permuted
    const float* __restrict__ cInit,          // dec: [B][256] f32
    const unsigned short* __restrict__ hInit, // dec: [B][256] bf16
    const float* __restrict__ initS,          // dec: [B][4]
    const float* __restrict__ Wc,             // dec: [256][2]
    const float* __restrict__ bc,             // dec: [2]
    unsigned short* __restrict__ hOut,        // enc: [B][256] bf16
    float* __restrict__ recons)               // dec: [B][T][4]
{
    __shared__ __align__(16) unsigned short hBuf[2][32 * 264];  // h ping-pong, unit-indexed
    __shared__ float wxL[4 * 1024];
    __shared__ float bfL[1024];
    __shared__ float WcL[512];
    __shared__ float sL[RB * 4];
    __shared__ float redL[RB * 8 * 2];

    const int tid = threadIdx.x;
    const int lane = tid & 63;
    const int fr = lane & 15;
    const int kg = lane >> 4;
    const int cg = tid >> 6;          // wave 0..7: owns cols [cg*128, cg*128+128)
    const int rowBase = blockIdx.x * RB;

    // ---- prologue ----
    #pragma unroll
    for (int w = 0; w < 2; ++w) {
        int cid = tid + w * 512;                  // 1024 chunks of 8 shorts
        int row = cid >> 5, seg = cid & 31;
        if (DEC) *(short8*)(&hBuf[0][row * 264 + seg * 8]) =
                     *(const short8*)(hInit + (size_t)(rowBase + row) * 256 + seg * 8);
        else {
            short8 z = {0, 0, 0, 0, 0, 0, 0, 0};
            *(short8*)(&hBuf[0][row * 264 + seg * 8]) = z;
        }
    }
    #pragma unroll
    for (int w = 0; w < 8; ++w) wxL[tid + w * 512] = WxP[tid + w * 512];
    #pragma unroll
    for (int w = 0; w < 2; ++w) bfL[tid + w * 512] = bfP[tid + w * 512];
    if (DEC) {
        if (tid < 128) *(float4*)(WcL + tid * 4) = *(const float4*)(Wc + tid * 4);
        if (tid < RB)  *(float4*)(sL + tid * 4) = *(const float4*)(initS + (size_t)(rowBase + tid) * 4);
    }
    float bc0 = 0.f, bc1 = 0.f;
    if (DEC && tid < RB) { bc0 = bc[0]; bc1 = bc[1]; }

    // c in registers: [sc][m][rr] ; unit u = (cg*2+sc)*16+fr, row = m*16+kg*4+rr
    float cReg[16];
    #pragma unroll
    for (int sc = 0; sc < 2; ++sc)
        #pragma unroll
        for (int m = 0; m < 2; ++m)
            #pragma unroll
            for (int rr = 0; rr < 4; ++rr) {
                if (DEC) cReg[sc * 8 + m * 4 + rr] =
                    cInit[(size_t)(rowBase + m * 16 + kg * 4 + rr) * 256 + (cg * 2 + sc) * 16 + fr];
                else cReg[sc * 8 + m * 4 + rr] = 0.f;
            }
    float hC[16];

    __syncthreads();

    for (int t = 0; t < T_; ++t) {
        const unsigned short* rbuf = hBuf[t & 1];
        unsigned short* wbuf = hBuf[(t + 1) & 1];

        // A-fragments: rows m*16+fr, k-chunk kg (all 256 k)
        short8 afr[2][8];
        #pragma unroll
        for (int m = 0; m < 2; ++m)
            #pragma unroll
            for (int k0 = 0; k0 < 8; ++k0)
                afr[m][k0] = *(const short8*)(rbuf + (m * 16 + fr) * 264 + (k0 * 4 + kg) * 8);

        #pragma unroll
        for (int sc = 0; sc < 2; ++sc) {
            const unsigned short* wbase = Wpk + (size_t)(cg * 2 + sc) * 4 * 4096 + lane * 8;
            // 4-deep k0 prefetch rotation
            short8 bq[4][4];
            #pragma unroll
            for (int p = 0; p < 4; ++p)
                #pragma unroll
                for (int n = 0; n < 4; ++n)
                    bq[p][n] = *(const short8*)(wbase + n * 4096 + p * 512);

            // x vectors for epilogue (issue early; consumed after MFMAs)
            float4 xv[2][4];
            #pragma unroll
            for (int m = 0; m < 2; ++m)
                #pragma unroll
                for (int rr = 0; rr < 4; ++rr) {
                    int row = m * 16 + kg * 4 + rr;
                    if (DEC) xv[m][rr] = *(const float4*)(sL + row * 4);
                    else     xv[m][rr] = *(const float4*)(rel + ((size_t)(rowBase + row) * T_ + t) * 4);
                }

            f32x4 acc[2][4] = {};
            #pragma unroll
            for (int k0 = 0; k0 < 8; ++k0) {
                #pragma unroll
                for (int m = 0; m < 2; ++m)
                    #pragma unroll
                    for (int n = 0; n < 4; ++n)
                        acc[m][n] = __builtin_amdgcn_mfma_f32_16x16x32_bf16(
                            afr[m][k0], bq[k0 & 3][n], acc[m][n], 0, 0, 0);
                if (k0 + 4 < 8) {
                    #pragma unroll
                    for (int n = 0; n < 4; ++n)
                        bq[k0 & 3][n] = *(const short8*)(wbase + n * 4096 + (k0 + 4) * 512);
                }
            }

            // epilogue: unit u = (cg*2+sc)*16+fr, gate g = acc[m][g]
            const int bn = cg * 2 + sc;
            const int np0 = bn * 64 + fr;
            const int u = bn * 16 + fr;
            float bfv[4], wxv[4][4];
            #pragma unroll
            for (int g = 0; g < 4; ++g) bfv[g] = bfL[np0 + g * 16];
            #pragma unroll
            for (int k = 0; k < 4; ++k)
                #pragma unroll
                for (int g = 0; g < 4; ++g)
                    wxv[k][g] = wxL[k * 1024 + np0 + g * 16];
            #pragma unroll
            for (int m = 0; m < 2; ++m) {
                #pragma unroll
                for (int rr = 0; rr < 4; ++rr) {
                    int row = m * 16 + kg * 4 + rr;
                    float xk[4] = {xv[m][rr].x, xv[m][rr].y, xv[m][rr].z, xv[m][rr].w};
                    float g0 = acc[m][0][rr] + bfv[0];
                    float g1 = acc[m][1][rr] + bfv[1];
                    float g2 = acc[m][2][rr] + bfv[2];
                    float g3 = acc[m][3][rr] + bfv[3];
                    #pragma unroll
                    for (int k = 0; k < 4; ++k) {
                        g0 = fmaf(xk[k], wxv[k][0], g0);
                        g1 = fmaf(xk[k], wxv[k][1], g1);
                        g2 = fmaf(xk[k], wxv[k][2], g2);
                        g3 = fmaf(xk[k], wxv[k][3], g3);
                    }
                    float iv = fast_sigmoid(g0);
                    float fv = fast_sigmoid(g1);
                    float gv = fast_tanh(g2);
                    float ov = fast_sigmoid(g3);
                    int ci = sc * 8 + m * 4 + rr;
                    float cn = fv * cReg[ci] + iv * gv;
                    cReg[ci] = cn;
                    float hval = ov * fast_tanh(cn);
                    if (DEC) hC[ci] = hval;
                    wbuf[row * 264 + u] = f2bf(hval);
                }
            }
        }

        if (DEC) {
            // ctrl head partials: per lane, 8 rows x 2 units
            float p0[8], p1[8];
            #pragma unroll
            for (int i = 0; i < 8; ++i) { p0[i] = 0.f; p1[i] = 0.f; }
            #pragma unroll
            for (int sc = 0; sc < 2; ++sc) {
                int u = (cg * 2 + sc) * 16 + fr;
                float w0 = WcL[u * 2], w1 = WcL[u * 2 + 1];
                #pragma unroll
                for (int m = 0; m < 2; ++m)
                    #pragma unroll
                    for (int rr = 0; rr < 4; ++rr) {
                        p0[m * 4 + rr] = fmaf(hC[sc * 8 + m * 4 + rr], w0, p0[m * 4 + rr]);
                        p1[m * 4 + rr] = fmaf(hC[sc * 8 + m * 4 + rr], w1, p1[m * 4 + rr]);
                    }
            }
            #pragma unroll
            for (int msk = 1; msk < 16; msk <<= 1)
                #pragma unroll
                for (int i = 0; i < 8; ++i) {
                    p0[i] += __shfl_xor(p0[i], msk);
                    p1[i] += __shfl_xor(p1[i], msk);
                }
            if (fr == 0) {
                #pragma unroll
                for (int m = 0; m < 2; ++m)
                    #pragma unroll
                    for (int rr = 0; rr < 4; ++rr) {
                        int row = m * 16 + kg * 4 + rr;
                        redL[(row * 8 + cg) * 2 + 0] = p0[m * 4 + rr];
                        redL[(row * 8 + cg) * 2 + 1] = p1[m * 4 + rr];
                    }
            }
            __syncthreads();
            if (tid < RB) {
                float q0 = 0.f, q1 = 0.f;
                #pragma unroll
                for (int w = 0; w < 8; ++w) {
                    q0 += redL[(tid * 8 + w) * 2 + 0];
                    q1 += redL[(tid * 8 + w) * 2 + 1];
                }
                float pedal = q0 + bc0;
                float steer = fminf(fmaxf(q1 + bc1, -0.5f), 0.5f);
                float4 sv = *(float4*)(sL + tid * 4);
                float v = sv.w;
                float v1 = fminf(fmaxf(v + pedal * DT_, 0.f), 10.f);
                float pd = fminf(fmaxf(v * tanf(steer) * (1.f / 2.5f), -1.57f), 1.57f);
                float4 ns;
                ns.x = sv.x + v1 * cosf(sv.z) * DT_;
                ns.y = sv.y + v1 * sinf(sv.z) * DT_;
                ns.z = sv.z + pd * DT_;
                ns.w = v1;
                *(float4*)(sL + tid * 4) = ns;
                *(float4*)(recons + ((size_t)(rowBase + tid) * T_ + t) * 4) = ns;
            }
            __syncthreads();
        } else {
            __syncthreads();
        }
    }

    if (!DEC) {   // final h (in hBuf[0] since T_ is even) -> global
        #pragma unroll
        for (int w = 0; w < 2; ++w) {
            int cid = tid + w * 512;
            int row = cid >> 5, seg = cid & 31;
            *(short8*)(hOut + (size_t)(rowBase + row) * 256 + seg * 8) =
                *(const short8*)(&hBuf[T_ & 1][row * 264 + seg * 8]);
        }
    }
}

// ---------- MFMA GEMM for MLP layers (z-batched) ----------
__global__ __launch_bounds__(256) void mlp_gemm_kernel(
    const unsigned short* __restrict__ Ain, size_t aZStride,
    const unsigned short* __restrict__ WTb, size_t wZStride,
    const float* __restrict__ b0, const float* __restrict__ b1,
    float* __restrict__ outF, size_t ofZStride,
    unsigned short* __restrict__ outB, size_t obZStride,
    int act)
{
    const int z = blockIdx.z;
    const unsigned short* A  = Ain + (size_t)z * aZStride;
    const unsigned short* WT = WTb + (size_t)z * wZStride;
    const float* bias = z ? b1 : b0;

    __shared__ __align__(16) short sA[64 * 256];
    __shared__ __align__(16) short sBm[64 * 256];
    const int tid = threadIdx.x;
    const int lane = tid & 63;
    const int wr = (tid >> 7) & 1;
    const int wc = (tid >> 6) & 1;
    const int rowBase = blockIdx.x * 64;
    const int nBase = blockIdx.y * 64;

    {
        const unsigned short* gA = A + (size_t)rowBase * 256;
        const unsigned short* gB = WT + (size_t)nBase * 256;
        #pragma unroll
        for (int i = 0; i < 8; ++i) {
            int ch = tid + i * 256;
            int row = ch >> 5, slot = ch & 31;
            float4 va = *(const float4*)(gA + row * 256 + slot * 8);
            float4 vb = *(const float4*)(gB + row * 256 + slot * 8);
            int sl = slot ^ (row & 7);
            *(float4*)(sA + row * 256 + sl * 8) = va;
            *(float4*)(sBm + row * 256 + sl * 8) = vb;
        }
    }
    __syncthreads();

    const int fr = lane & 15;
    const int kg = lane >> 4;
    f32x4 acc[2][2] = {};
    #pragma unroll
    for (int k0 = 0; k0 < 8; ++k0) {
        int kch = k0 * 4 + kg;
        short8 a[2], b[2];
        #pragma unroll
        for (int m = 0; m < 2; ++m) {
            int r = wr * 32 + m * 16 + fr;
            a[m] = *(const short8*)(sA + r * 256 + (kch ^ (r & 7)) * 8);
        }
        #pragma unroll
        for (int n = 0; n < 2; ++n) {
            int r = wc * 32 + n * 16 + fr;
            b[n] = *(const short8*)(sBm + r * 256 + (kch ^ (r & 7)) * 8);
        }
        #pragma unroll
        for (int m = 0; m < 2; ++m)
            #pragma unroll
            for (int n = 0; n < 2; ++n)
                acc[m][n] = __builtin_amdgcn_mfma_f32_16x16x32_bf16(a[m], b[n], acc[m][n], 0, 0, 0);
    }

    #pragma unroll
    for (int m = 0; m < 2; ++m) {
        #pragma unroll
        for (int n = 0; n < 2; ++n) {
            int col = nBase + wc * 32 + n * 16 + fr;
            float bv = bias[col];
            #pragma unroll
            for (int r = 0; r < 4; ++r) {
                int row = rowBase + wr * 32 + m * 16 + kg * 4 + r;
                float v = acc[m][n][r] + bv;
                if (act) v = v > 0.f ? v : 0.01f * v;
                if (outF) outF[(size_t)z * ofZStride + (size_t)row * H_ + col] = v;
                if (outB) outB[(size_t)z * obZStride + (size_t)row * H_ + col] = f2bf(v);
            }
        }
    }
}

// ---------- z = tanh(eps*exp(0.5*lv)+mu) -> bf16 ----------
__global__ void z_kernel(const float* __restrict__ eps, const float* __restrict__ mu,
                         const float* __restrict__ lv, unsigned short* __restrict__ z) {
    int id = blockIdx.x * blockDim.x + threadIdx.x;
    z[id] = f2bf(tanhf(eps[id] * expf(0.5f * lv[id]) + mu[id]));
}

extern "C" void kernel_launch(void* const* d_in, const int* in_sizes, int n_in,
                              void* d_out, int out_size, void* d_ws, size_t ws_size,
                              hipStream_t stream) {
    (void)in_sizes; (void)n_in; (void)out_size; (void)ws_size;
    const float* traj       = (const float*)d_in[0];
    const float* init_s     = (const float*)d_in[1];
    const float* eps        = (const float*)d_in[2];
    const float* enc_emb_W  = (const float*)d_in[3];
    const float* enc_emb_b  = (const float*)d_in[4];
    const float* enc_Wih    = (const float*)d_in[5];
    const float* enc_bih    = (const float*)d_in[6];
    const float* enc_Whh    = (const float*)d_in[7];
    const float* enc_bhh    = (const float*)d_in[8];
    const float* mu_W       = (const float*)d_in[9];
    const float* mu_b       = (const float*)d_in[10];
    const float* lv_W       = (const float*)d_in[11];
    const float* lv_b       = (const float*)d_in[12];
    const float* dec_emb_W  = (const float*)d_in[13];
    const float* dec_emb_b  = (const float*)d_in[14];
    const float* dec_init_W = (const float*)d_in[15];
    const float* dec_init_b = (const float*)d_in[16];
    const float* dec_Wih    = (const float*)d_in[17];
    const float* dec_bih    = (const float*)d_in[18];
    const float* dec_Whh    = (const float*)d_in[19];
    const float* dec_bhh    = (const float*)d_in[20];
    const float* ctrl_W     = (const float*)d_in[21];
    const float* ctrl_b     = (const float*)d_in[22];

    float* out = (float*)d_out;
    float* recons = out;                              // B*T*4
    float* expert = out + (size_t)B_ * T_ * 4;        // B*T*4
    float* mu_out = expert + (size_t)B_ * T_ * 4;     // B*H
    float* lv_out = mu_out + (size_t)B_ * H_;         // B*H

    float* ws = (float*)d_ws;
    size_t o = 0;
    float* rel = ws + o;  o += (size_t)B_ * T_ * 4;
    unsigned short* WpkE = (unsigned short*)(ws + o); o += NG_ * H_ / 2;
    unsigned short* WpkD = (unsigned short*)(ws + o); o += NG_ * H_ / 2;
    unsigned short* WT9  = (unsigned short*)(ws + o); o += 9 * H_ * H_ / 2;
    float* WxPE = ws + o; o += 4 * NG_;
    float* WxPD = ws + o; o += 4 * NG_;
    float* bfPE = ws + o; o += NG_;
    float* bfPD = ws + o; o += NG_;
    unsigned short* hEnc = (unsigned short*)(ws + o); o += (size_t)B_ * H_ / 2;
    unsigned short* tbA  = (unsigned short*)(ws + o); o += (size_t)B_ * H_;  // 2 z-slots
    unsigned short* tbB  = (unsigned short*)(ws + o); o += (size_t)B_ * H_;  // 2 z-slots
    float* cInit = ws + o; o += (size_t)B_ * H_;
    unsigned short* hInit = (unsigned short*)(ws + o); o += (size_t)B_ * H_ / 2;

    // ---- prep ----
    fold_perm_kernel<<<80, 256, 0, stream>>>(enc_emb_W, enc_emb_b, enc_Wih, enc_bih, enc_bhh, WxPE, bfPE);
    fold_perm_kernel<<<80, 256, 0, stream>>>(dec_emb_W, dec_emb_b, dec_Wih, dec_bih, dec_bhh, WxPD, bfPD);
    prep_pack_kernel<<<1024, 256, 0, stream>>>(enc_Whh, WpkE);
    prep_pack_kernel<<<1024, 256, 0, stream>>>(dec_Whh, WpkD);
    prep_wt_all_kernel<<<dim3(256, 9), 256, 0, stream>>>(mu_W, lv_W, dec_init_W, WT9);
    rel_kernel<<<(B_ * T_ + 255) / 256, 256, 0, stream>>>(traj, rel, (float4*)expert);

    // ---- encoder (one persistent launch) ----
    lstm_persist3_kernel<0><<<NBLK, 512, 0, stream>>>(
        rel, WpkE, WxPE, bfPE, nullptr, nullptr, nullptr, nullptr, nullptr, hEnc, nullptr);

    // ---- mu/lv MLPs, z-batched ----
    dim3 gridM2(B_ / 64, H_ / 64, 2);
    size_t BH = (size_t)B_ * H_;
    mlp_gemm_kernel<<<gridM2, 256, 0, stream>>>(hEnc, 0, WT9 + 0 * 65536, (size_t)4 * 65536,
                                                mu_b + 0,   lv_b + 0,   nullptr, 0, tbA, BH, 1);
    mlp_gemm_kernel<<<gridM2, 256, 0, stream>>>(tbA, BH, WT9 + 1 * 65536, (size_t)4 * 65536,
                                                mu_b + 256, lv_b + 256, nullptr, 0, tbB, BH, 1);
    mlp_gemm_kernel<<<gridM2, 256, 0, stream>>>(tbB, BH, WT9 + 2 * 65536, (size_t)4 * 65536,
                                                mu_b + 512, lv_b + 512, nullptr, 0, tbA, BH, 1);
    mlp_gemm_kernel<<<gridM2, 256, 0, stream>>>(tbA, BH, WT9 + 3 * 65536, (size_t)4 * 65536,
                                                mu_b + 768, lv_b + 768, mu_out, BH, nullptr, 0, 1);

    // ---- z, decoder init ----
    z_kernel<<<B_ * H_ / 256, 256, 0, stream>>>(eps, mu_out, lv_out, tbB);
    dim3 gridM1(B_ / 64, H_ / 64, 1);
    mlp_gemm_kernel<<<gridM1, 256, 0, stream>>>(tbB, 0, WT9 + 8 * 65536, 0,
                                                dec_init_b, dec_init_b, cInit, 0, hInit, 0, 0);

    // ---- decoder (one persistent launch) ----
    lstm_persist3_kernel<1><<<NBLK, 512, 0, stream>>>(
        nullptr, WpkD, WxPD, bfPD, cInit, hInit, init_s, ctrl_W, ctrl_b, nullptr, recons);
}